// Round 7
// baseline (384.893 us; speedup 1.0000x reference)
//
#include <hip/hip_runtime.h>
#include <math.h>

#define NB 8
#define NC 256
#define ND 32
#define NN 4096
#define NM 320                 // fused rows: 32 q + 32 k + 256 v
#define LOG2E 1.44269504088896f
#define XSTR 264               // proj LDS row stride (shorts), 16B-aligned rows

typedef short short8 __attribute__((ext_vector_type(8)));
typedef float f32x4 __attribute__((ext_vector_type(4)));

// LDS-only barrier: drains ds ops, leaves global loads in flight.
#define LDS_BARRIER() asm volatile("s_waitcnt lgkmcnt(0)\ns_barrier" ::: "memory")

__device__ __forceinline__ unsigned int f2bf_u(float f) {
    return (__float_as_uint(f) + 0x8000u) >> 16;
}
__device__ __forceinline__ unsigned short f2bf(float f) {
    return (unsigned short)f2bf_u(f);
}

// ---------------------------------------------------------------------------
// Repack fused weights [320x256] -> bf16 fragments (per-lane: row li of the
// 16-row tile, k-window qd*8..+8).  Rows 0..31 = Wq*LOG2E, 32..63 = Wk,
// 64..319 = Wv.  Also bias[320].
// ---------------------------------------------------------------------------
__global__ __launch_bounds__(256) void repack_kernel(
    const float* __restrict__ Wq, const float* __restrict__ bq,
    const float* __restrict__ Wk, const float* __restrict__ bk,
    const float* __restrict__ Wv, const float* __restrict__ bv,
    unsigned short* __restrict__ wp, float* __restrict__ bias)
{
    const int T    = blockIdx.x * 256 + threadIdx.x;   // 81920 threads
    const int j    = T & 7;
    const int lane = (T >> 3) & 63;
    const int ks   = (T >> 9) & 7;
    const int mt   = T >> 12;
    const int m = mt * 16 + (lane & 15);
    const int k = ks * 32 + ((lane >> 4) << 3) + j;
    float wv;
    if (m < 32)       wv = Wq[m * NC + k] * LOG2E;
    else if (m < 64)  wv = Wk[(m - 32) * NC + k];
    else              wv = Wv[(m - 64) * NC + k];
    wp[T] = f2bf(wv);
    if (T < NM) {
        float bb;
        if (T < 32)      bb = bq[T] * LOG2E;
        else if (T < 64) bb = bk[T - 32];
        else             bb = bv[T - 64];
        bias[T] = bb;
    }
}

// ---------------------------------------------------------------------------
// MFMA projection, operand-swapped: A = x (m = pixel), B = W^T (n = out row).
// D lane layout: col(li) = out-row-within-tile, row(4qd+r) = pixel -> the 4
// acc elements are 4 CONSECUTIVE PIXELS => packed uint2 stores for v.
// Block = (batch, 32-px tile), 4 waves, grid 1024.
// ---------------------------------------------------------------------------
__global__ __launch_bounds__(256, 4) void proj_kernel(
    const float* __restrict__ x,
    const unsigned short* __restrict__ wp,
    const float* __restrict__ bias,
    unsigned short* __restrict__ q_ws,
    unsigned short* __restrict__ k_ws,
    unsigned short* __restrict__ v_ws)
{
    __shared__ __align__(16) unsigned short xs[32 * XSTR];   // 16.9 KB

    const int b  = blockIdx.x >> 7;          // 128 tiles per batch
    const int n0 = (blockIdx.x & 127) << 5;
    const int t  = threadIdx.x;

    // ---- stage + convert x tile [32 px][256 ch] ----
    {
        const int n  = t & 31;
        const int cg = t >> 5;               // 0..7
        const float* xb = x + (size_t)b * NC * NN + n0 + n;
        #pragma unroll
        for (int it = 0; it < 8; ++it) {
            const int c = 32 * it + 4 * cg;
            const float x0 = xb[(size_t)(c + 0) * NN];
            const float x1 = xb[(size_t)(c + 1) * NN];
            const float x2 = xb[(size_t)(c + 2) * NN];
            const float x3 = xb[(size_t)(c + 3) * NN];
            uint2 pk;
            pk.x = (f2bf_u(x1) << 16) | f2bf_u(x0);
            pk.y = (f2bf_u(x3) << 16) | f2bf_u(x2);
            *(uint2*)(xs + n * XSTR + c) = pk;
        }
    }
    __syncthreads();

    const int w    = t >> 6;
    const int lane = t & 63;
    const int li = lane & 15;
    const int qd = lane >> 4;

    // acc[u][mt]: out-tile ct = w+4u (n-dim), pixel-tile mt (m-dim)
    f32x4 acc[5][2];
    #pragma unroll
    for (int u = 0; u < 5; ++u) {
        const float bb = bias[(w + 4 * u) * 16 + li];   // depends on out-row only
        acc[u][0] = (f32x4){bb, bb, bb, bb};
        acc[u][1] = (f32x4){bb, bb, bb, bb};
    }

    #pragma unroll
    for (int ks = 0; ks < 8; ++ks) {
        short8 af[2];   // x fragments (A): row = pixel li of tile mt
        #pragma unroll
        for (int mt = 0; mt < 2; ++mt)
            af[mt] = *(const short8*)(xs + (mt * 16 + li) * XSTR + ks * 32 + qd * 8);
        #pragma unroll
        for (int u = 0; u < 5; ++u) {
            const int ct = w + 4 * u;
            const short8 bf = *(const short8*)(wp + (size_t)((ct * 8 + ks) * 64 + lane) * 8);
            acc[u][0] = __builtin_amdgcn_mfma_f32_16x16x32_bf16(af[0], bf, acc[u][0], 0, 0, 0);
            acc[u][1] = __builtin_amdgcn_mfma_f32_16x16x32_bf16(af[1], bf, acc[u][1], 0, 0, 0);
        }
    }

    #pragma unroll
    for (int u = 0; u < 5; ++u) {
        const int ct = w + 4 * u;            // wave-uniform
        if (ct < 4) {                        // q/k (u==0, w<4): scalar stores, tiny
            unsigned short* dst = (ct < 2) ? q_ws : k_ws;
            const int d = (ct & 1) * 16 + li;
            #pragma unroll
            for (int mt = 0; mt < 2; ++mt)
                #pragma unroll
                for (int r = 0; r < 4; ++r) {
                    const int n = n0 + mt * 16 + 4 * qd + r;
                    dst[((size_t)b * NN + n) * ND + d] = f2bf(acc[u][mt][r]);
                }
        } else {
            const int cv = (ct - 4) * 16 + li;
            #pragma unroll
            for (int mt = 0; mt < 2; ++mt) {
                const int n = n0 + mt * 16 + 4 * qd;   // 4 consecutive pixels
                uint2 pk;
                pk.x = (f2bf_u(acc[u][mt][1]) << 16) | f2bf_u(acc[u][mt][0]);
                pk.y = (f2bf_u(acc[u][mt][3]) << 16) | f2bf_u(acc[u][mt][2]);
                *(uint2*)(v_ws + ((size_t)b * NC + cv) * NN + n) = pk;
            }
        }
    }
}

// ---------------------------------------------------------------------------
// Flash attention.  Block = 4 waves (256 thr), i-tile 32 (2 strips),
// c-half 128; grid = 8 * 128 * 2 = 2048 (8 block-slots/CU).
// Wave w: S-duty strip sw=w&1, j-half th=w>>1 (2 MFMA + 8 exp2 / chunk);
// PV-duty 32 channels c0=ch+32w (8 MFMA / chunk).  P double-buffered in LDS;
// raw LDS-only barrier per chunk keeps global loads in flight across it.
// ---------------------------------------------------------------------------
__global__ __launch_bounds__(256, 4) void attn_kernel(
    const unsigned short* __restrict__ q_ws,
    const unsigned short* __restrict__ k_ws,
    const unsigned short* __restrict__ v_ws,
    float* __restrict__ out)
{
    __shared__ __align__(16) unsigned short Pb[2][2][16 * 72];  // 9 KB
    __shared__ float lred[4][16];

    const int b   = blockIdx.x & 7;          // batch == XCD
    const int idx = blockIdx.x >> 3;         // 128 i-tiles x 2 c-halves
    const int i0  = (idx >> 1) * 32;
    const int ch  = (idx & 1) * 128;
    const int w    = threadIdx.x >> 6;
    const int lane = threadIdx.x & 63;
    const int li = lane & 15;
    const int qd = lane >> 4;
    const int sw = w & 1;                    // S strip duty
    const int th = w >> 1;                   // S j-half duty
    const int c0 = ch + 32 * w;              // PV channel slice

    const short8 qf = *(const short8*)(q_ws + ((size_t)b * NN + i0 + 16 * sw + li) * ND + qd * 8);
    const unsigned short* kb  = k_ws + ((size_t)b * NN + 32 * th + li) * ND + qd * 8;
    const unsigned short* vb0 = v_ws + ((size_t)b * NC + c0 + li) * NN + qd * 8;
    const unsigned short* vb1 = vb0 + (size_t)16 * NN;

    unsigned short* PA = &Pb[0][0][0];
    unsigned short* PB = &Pb[1][0][0];

    f32x4 o[2][2];
    o[0][0] = (f32x4){0,0,0,0}; o[0][1] = (f32x4){0,0,0,0};
    o[1][0] = (f32x4){0,0,0,0}; o[1][1] = (f32x4){0,0,0,0};
    float l_loc = 0.f;
    const f32x4 z4 = {0.f, 0.f, 0.f, 0.f};

    short8 kf[2], vfA[2][2], vfB[2][2];

    auto LKF = [&](int j0) {
        kf[0] = *(const short8*)(kb + (size_t)(j0     ) * ND);
        kf[1] = *(const short8*)(kb + (size_t)(j0 + 16) * ND);
    };
    auto LVF = [&](int j0, short8 (&vf)[2][2]) {
        vf[0][0] = *(const short8*)(vb0 + j0);
        vf[0][1] = *(const short8*)(vb0 + j0 + 32);
        vf[1][0] = *(const short8*)(vb1 + j0);
        vf[1][1] = *(const short8*)(vb1 + j0 + 32);
    };
    auto DOS = [&](unsigned short* P) {
        // write j-locals 32*th + 16*tt + 4*qd + {0..3} of strip sw, row li
        unsigned short* Pw = P + (size_t)sw * (16 * 72) + li * 72 + 32 * th + 4 * qd;
        #pragma unroll
        for (int tt = 0; tt < 2; ++tt) {
            const f32x4 s = __builtin_amdgcn_mfma_f32_16x16x32_bf16(kf[tt], qf, z4, 0, 0, 0);
            const float p0 = __builtin_amdgcn_exp2f(s[0]);
            const float p1 = __builtin_amdgcn_exp2f(s[1]);
            const float p2 = __builtin_amdgcn_exp2f(s[2]);
            const float p3 = __builtin_amdgcn_exp2f(s[3]);
            l_loc += (p0 + p1) + (p2 + p3);
            const unsigned u0 = __float_as_uint(p0) + 0x8000u;
            const unsigned u1 = __float_as_uint(p1) + 0x8000u;
            const unsigned u2 = __float_as_uint(p2) + 0x8000u;
            const unsigned u3 = __float_as_uint(p3) + 0x8000u;
            uint2 pk;
            pk.x = __builtin_amdgcn_perm(u1, u0, 0x07060302u);
            pk.y = __builtin_amdgcn_perm(u3, u2, 0x07060302u);
            *(uint2*)(Pw + 16 * tt) = pk;
        }
    };
    auto DOPV = [&](const unsigned short* P, const short8 (&vf)[2][2]) {
        #pragma unroll
        for (int s = 0; s < 2; ++s) {
            const unsigned short* Pr = P + (size_t)s * (16 * 72) + li * 72 + qd * 8;
            const short8 pf0 = *(const short8*)(Pr);
            const short8 pf1 = *(const short8*)(Pr + 32);
            o[s][0] = __builtin_amdgcn_mfma_f32_16x16x32_bf16(vf[0][0], pf0, o[s][0], 0, 0, 0);
            o[s][0] = __builtin_amdgcn_mfma_f32_16x16x32_bf16(vf[0][1], pf1, o[s][0], 0, 0, 0);
            o[s][1] = __builtin_amdgcn_mfma_f32_16x16x32_bf16(vf[1][0], pf0, o[s][1], 0, 0, 0);
            o[s][1] = __builtin_amdgcn_mfma_f32_16x16x32_bf16(vf[1][1], pf1, o[s][1], 0, 0, 0);
        }
    };

    // ---- pipelined main loop ----
    LKF(0); LVF(0, vfA);
    DOS(PA);
    LDS_BARRIER();
    int j0 = 64;
    for (int it = 0; it < 31; ++it) {
        LKF(j0); LVF(j0, vfB);
        DOPV(PA, vfA);
        DOS(PB);
        LDS_BARRIER();
        j0 += 64;
        LKF(j0); LVF(j0, vfA);
        DOPV(PB, vfB);
        DOS(PA);
        LDS_BARRIER();
        j0 += 64;
    }
    LKF(j0); LVF(j0, vfB);      // chunk 63
    DOPV(PA, vfA);
    DOS(PB);
    LDS_BARRIER();
    DOPV(PB, vfB);

    // ---- l reduction: qd via shuffle, j-halves via LDS ----
    l_loc += __shfl_xor(l_loc, 16, 64);
    l_loc += __shfl_xor(l_loc, 32, 64);
    if (lane < 16) lred[w][li] = l_loc;
    __syncthreads();
    float linv[2];
    linv[0] = 1.0f / (lred[0][li] + lred[2][li]);
    linv[1] = 1.0f / (lred[1][li] + lred[3][li]);

    #pragma unroll
    for (int s = 0; s < 2; ++s)
        #pragma unroll
        for (int mt = 0; mt < 2; ++mt) {
            const int c = c0 + mt * 16 + qd * 4;
            float* op = out + ((size_t)b * NC + c) * NN + i0 + 16 * s + li;
            #pragma unroll
            for (int r = 0; r < 4; ++r)
                op[(size_t)r * NN] = o[s][mt][r] * linv[s];
        }
}

// ---------------------------------------------------------------------------
extern "C" void kernel_launch(void* const* d_in, const int* in_sizes, int n_in,
                              void* d_out, int out_size, void* d_ws, size_t ws_size,
                              hipStream_t stream) {
    const float* x  = (const float*)d_in[0];
    const float* Wq = (const float*)d_in[1];
    const float* bq = (const float*)d_in[2];
    const float* Wk = (const float*)d_in[3];
    const float* bk = (const float*)d_in[4];
    const float* Wv = (const float*)d_in[5];
    const float* bv = (const float*)d_in[6];
    float* out = (float*)d_out;

    unsigned short* q_ws = (unsigned short*)d_ws;            // 2 MB
    unsigned short* k_ws = q_ws + (size_t)NB * NN * ND;      // 2 MB
    unsigned short* v_ws = k_ws + (size_t)NB * NN * ND;      // 16 MB
    unsigned short* wp   = v_ws + (size_t)NB * NC * NN;      // 160 KB
    float*          bias = (float*)(wp + (size_t)NM * NC);   // 1.25 KB

    repack_kernel<<<NM * NC / 256, 256, 0, stream>>>(Wq, bq, Wk, bk, Wv, bv, wp, bias);
    proj_kernel<<<NB * (NN / 32), 256, 0, stream>>>(x, wp, bias, q_ws, k_ws, v_ws);
    attn_kernel<<<NB * (NN / 32) * 2, 256, 0, stream>>>(q_ws, k_ws, v_ws, out);
}

// Round 8
// 247.642 us; speedup vs baseline: 1.5542x; 1.5542x over previous
//
#include <hip/hip_runtime.h>
#include <math.h>

#define NB 8
#define NC 256
#define ND 32
#define NN 4096
#define NM 320                 // fused rows: 32 q + 32 k + 256 v
#define LOG2E 1.44269504088896f
#define XSTR 264               // proj LDS row stride (shorts), 16B-aligned rows

typedef short short8 __attribute__((ext_vector_type(8)));
typedef float f32x4 __attribute__((ext_vector_type(4)));

// LDS-only barrier: drains ds ops, leaves global loads in flight (vmcnt
// untouched) — compiler inserts fine-grained vmcnt(N) at first use.
#define LDS_BARRIER() asm volatile("s_waitcnt lgkmcnt(0)\ns_barrier" ::: "memory")

__device__ __forceinline__ unsigned int f2bf_u(float f) {
    return (__float_as_uint(f) + 0x8000u) >> 16;
}
__device__ __forceinline__ unsigned short f2bf(float f) {
    return (unsigned short)f2bf_u(f);
}

// ---------------------------------------------------------------------------
// Repack fused weights [320x256] -> bf16 fragments.  Rows 0..31 = Wq*LOG2E,
// 32..63 = Wk, 64..319 = Wv.  Also bias[320].
// ---------------------------------------------------------------------------
__global__ __launch_bounds__(256) void repack_kernel(
    const float* __restrict__ Wq, const float* __restrict__ bq,
    const float* __restrict__ Wk, const float* __restrict__ bk,
    const float* __restrict__ Wv, const float* __restrict__ bv,
    unsigned short* __restrict__ wp, float* __restrict__ bias)
{
    const int T    = blockIdx.x * 256 + threadIdx.x;   // 81920 threads
    const int j    = T & 7;
    const int lane = (T >> 3) & 63;
    const int ks   = (T >> 9) & 7;
    const int mt   = T >> 12;
    const int m = mt * 16 + (lane & 15);
    const int k = ks * 32 + ((lane >> 4) << 3) + j;
    float wv;
    if (m < 32)       wv = Wq[m * NC + k] * LOG2E;
    else if (m < 64)  wv = Wk[(m - 32) * NC + k];
    else              wv = Wv[(m - 64) * NC + k];
    wp[T] = f2bf(wv);
    if (T < NM) {
        float bb;
        if (T < 32)      bb = bq[T] * LOG2E;
        else if (T < 64) bb = bk[T - 32];
        else             bb = bv[T - 64];
        bias[T] = bb;
    }
}

// ---------------------------------------------------------------------------
// MFMA projection (unchanged from R7): A = x (m = pixel), B = W^T.
// ---------------------------------------------------------------------------
__global__ __launch_bounds__(256, 4) void proj_kernel(
    const float* __restrict__ x,
    const unsigned short* __restrict__ wp,
    const float* __restrict__ bias,
    unsigned short* __restrict__ q_ws,
    unsigned short* __restrict__ k_ws,
    unsigned short* __restrict__ v_ws)
{
    __shared__ __align__(16) unsigned short xs[32 * XSTR];   // 16.9 KB

    const int b  = blockIdx.x >> 7;          // 128 tiles per batch
    const int n0 = (blockIdx.x & 127) << 5;
    const int t  = threadIdx.x;

    {
        const int n  = t & 31;
        const int cg = t >> 5;               // 0..7
        const float* xb = x + (size_t)b * NC * NN + n0 + n;
        #pragma unroll
        for (int it = 0; it < 8; ++it) {
            const int c = 32 * it + 4 * cg;
            const float x0 = xb[(size_t)(c + 0) * NN];
            const float x1 = xb[(size_t)(c + 1) * NN];
            const float x2 = xb[(size_t)(c + 2) * NN];
            const float x3 = xb[(size_t)(c + 3) * NN];
            uint2 pk;
            pk.x = (f2bf_u(x1) << 16) | f2bf_u(x0);
            pk.y = (f2bf_u(x3) << 16) | f2bf_u(x2);
            *(uint2*)(xs + n * XSTR + c) = pk;
        }
    }
    __syncthreads();

    const int w    = t >> 6;
    const int lane = t & 63;
    const int li = lane & 15;
    const int qd = lane >> 4;

    f32x4 acc[5][2];
    #pragma unroll
    for (int u = 0; u < 5; ++u) {
        const float bb = bias[(w + 4 * u) * 16 + li];
        acc[u][0] = (f32x4){bb, bb, bb, bb};
        acc[u][1] = (f32x4){bb, bb, bb, bb};
    }

    #pragma unroll
    for (int ks = 0; ks < 8; ++ks) {
        short8 af[2];
        #pragma unroll
        for (int mt = 0; mt < 2; ++mt)
            af[mt] = *(const short8*)(xs + (mt * 16 + li) * XSTR + ks * 32 + qd * 8);
        #pragma unroll
        for (int u = 0; u < 5; ++u) {
            const int ct = w + 4 * u;
            const short8 bf = *(const short8*)(wp + (size_t)((ct * 8 + ks) * 64 + lane) * 8);
            acc[u][0] = __builtin_amdgcn_mfma_f32_16x16x32_bf16(af[0], bf, acc[u][0], 0, 0, 0);
            acc[u][1] = __builtin_amdgcn_mfma_f32_16x16x32_bf16(af[1], bf, acc[u][1], 0, 0, 0);
        }
    }

    #pragma unroll
    for (int u = 0; u < 5; ++u) {
        const int ct = w + 4 * u;
        if (ct < 4) {
            unsigned short* dst = (ct < 2) ? q_ws : k_ws;
            const int d = (ct & 1) * 16 + li;
            #pragma unroll
            for (int mt = 0; mt < 2; ++mt)
                #pragma unroll
                for (int r = 0; r < 4; ++r) {
                    const int n = n0 + mt * 16 + 4 * qd + r;
                    dst[((size_t)b * NN + n) * ND + d] = f2bf(acc[u][mt][r]);
                }
        } else {
            const int cv = (ct - 4) * 16 + li;
            #pragma unroll
            for (int mt = 0; mt < 2; ++mt) {
                const int n = n0 + mt * 16 + 4 * qd;
                uint2 pk;
                pk.x = (f2bf_u(acc[u][mt][1]) << 16) | f2bf_u(acc[u][mt][0]);
                pk.y = (f2bf_u(acc[u][mt][3]) << 16) | f2bf_u(acc[u][mt][2]);
                *(uint2*)(v_ws + ((size_t)b * NC + cv) * NN + n) = pk;
            }
        }
    }
}

// ---------------------------------------------------------------------------
// Flash attention, deep-pipelined.  Block = 8 waves (512 thr), i-tile 64,
// all 256 channels; grid = 512 (2 blocks/CU).
// Wave w: S-duty strip sw=w&3, j-half th=w>>2 (2 S-MFMA + 8 exp2/chunk);
// PV-duty 32 channels c0=32w (16 PV-MFMA/chunk).
// Pipeline (interval n): issue vf(n+1), PV(n), S(n+1) with kf prefetched a
// full interval earlier, issue kf(n+2), LDS-only barrier.  Global loads stay
// in flight across barriers (vmcnt(N) waits at first use, AITER-style).
// ---------------------------------------------------------------------------
__global__ __launch_bounds__(512, 4) void attn_kernel(
    const unsigned short* __restrict__ q_ws,
    const unsigned short* __restrict__ k_ws,
    const unsigned short* __restrict__ v_ws,
    float* __restrict__ out)
{
    __shared__ __align__(16) unsigned short Pb[2][4][16 * 72];  // 18.4 KB
    __shared__ float lred[8][16];

    const int b  = blockIdx.x & 7;           // batch == XCD
    const int i0 = (blockIdx.x >> 3) * 64;
    const int w    = threadIdx.x >> 6;       // 0..7
    const int lane = threadIdx.x & 63;
    const int li = lane & 15;
    const int qd = lane >> 4;
    const int sw = w & 3;                    // S strip duty
    const int th = w >> 2;                   // S j-half duty
    const int c0 = 32 * w;                   // PV channel slice

    const short8 qf = *(const short8*)(q_ws + ((size_t)b * NN + i0 + 16 * sw + li) * ND + qd * 8);
    const unsigned short* kb  = k_ws + ((size_t)b * NN + 32 * th + li) * ND + qd * 8;
    const unsigned short* vb0 = v_ws + ((size_t)b * NC + c0 + li) * NN + qd * 8;
    const unsigned short* vb1 = vb0 + (size_t)16 * NN;

    unsigned short* PA = &Pb[0][0][0];       // even chunks
    unsigned short* PB = &Pb[1][0][0];       // odd chunks

    f32x4 o[4][2];
    #pragma unroll
    for (int sb = 0; sb < 4; ++sb) { o[sb][0] = (f32x4){0,0,0,0}; o[sb][1] = (f32x4){0,0,0,0}; }
    float l_loc = 0.f;
    const f32x4 z4 = {0.f, 0.f, 0.f, 0.f};

    short8 kA[2], kB[2], vA[2][2], vB[2][2];

    auto LKF = [&](int j0, short8 (&kf)[2]) {
        kf[0] = *(const short8*)(kb + (size_t)(j0     ) * ND);
        kf[1] = *(const short8*)(kb + (size_t)(j0 + 16) * ND);
    };
    auto LVF = [&](int j0, short8 (&vf)[2][2]) {
        vf[0][0] = *(const short8*)(vb0 + j0);
        vf[0][1] = *(const short8*)(vb0 + j0 + 32);
        vf[1][0] = *(const short8*)(vb1 + j0);
        vf[1][1] = *(const short8*)(vb1 + j0 + 32);
    };
    auto DOS = [&](short8 (&kf)[2], unsigned short* P) {
        unsigned short* Pw = P + sw * (16 * 72) + li * 72 + 32 * th + 4 * qd;
        #pragma unroll
        for (int tt = 0; tt < 2; ++tt) {
            const f32x4 s = __builtin_amdgcn_mfma_f32_16x16x32_bf16(kf[tt], qf, z4, 0, 0, 0);
            const float p0 = __builtin_amdgcn_exp2f(s[0]);
            const float p1 = __builtin_amdgcn_exp2f(s[1]);
            const float p2 = __builtin_amdgcn_exp2f(s[2]);
            const float p3 = __builtin_amdgcn_exp2f(s[3]);
            l_loc += (p0 + p1) + (p2 + p3);
            const unsigned u0 = __float_as_uint(p0) + 0x8000u;
            const unsigned u1 = __float_as_uint(p1) + 0x8000u;
            const unsigned u2 = __float_as_uint(p2) + 0x8000u;
            const unsigned u3 = __float_as_uint(p3) + 0x8000u;
            uint2 pk;
            pk.x = __builtin_amdgcn_perm(u1, u0, 0x07060302u);
            pk.y = __builtin_amdgcn_perm(u3, u2, 0x07060302u);
            *(uint2*)(Pw + 16 * tt) = pk;
        }
    };
    auto DOPV = [&](const unsigned short* P, short8 (&vf)[2][2]) {
        #pragma unroll
        for (int sb = 0; sb < 4; ++sb) {
            const unsigned short* Pr = P + sb * (16 * 72) + li * 72 + qd * 8;
            const short8 pf0 = *(const short8*)(Pr);
            const short8 pf1 = *(const short8*)(Pr + 32);
            o[sb][0] = __builtin_amdgcn_mfma_f32_16x16x32_bf16(vf[0][0], pf0, o[sb][0], 0, 0, 0);
            o[sb][0] = __builtin_amdgcn_mfma_f32_16x16x32_bf16(vf[0][1], pf1, o[sb][0], 0, 0, 0);
            o[sb][1] = __builtin_amdgcn_mfma_f32_16x16x32_bf16(vf[1][0], pf0, o[sb][1], 0, 0, 0);
            o[sb][1] = __builtin_amdgcn_mfma_f32_16x16x32_bf16(vf[1][1], pf1, o[sb][1], 0, 0, 0);
        }
    };

    // ---- prologue: chunk 0 S exposed once; kf(1) prefetched ----
    LKF(0, kA); LVF(0, vA);
    DOS(kA, PA);
    LKF(64, kB);
    LDS_BARRIER();

    // ---- main loop: 31 double-intervals (chunks 0..61 PV, 1..62 S) ----
    int j = 0;
    #pragma unroll 1
    for (int it = 0; it < 31; ++it) {
        // interval n=2it (even): PV(n) | S(n+1) | prefetch v(n+1), k(n+2)
        LVF(j + 64, vB);
        DOPV(PA, vA);
        DOS(kB, PB);
        LKF(j + 128, kA);
        LDS_BARRIER();
        // interval n=2it+1 (odd)
        LVF(j + 128, vA);
        DOPV(PB, vB);
        DOS(kA, PA);
        LKF(j + 192, kB);
        LDS_BARRIER();
        j += 128;
    }
    // j = 3968: interval 62 (even): PV(62) | S(63)
    LVF(4032, vB);
    DOPV(PA, vA);
    DOS(kB, PB);
    LDS_BARRIER();
    DOPV(PB, vB);    // chunk 63

    // ---- l reduction: qd via shuffle, th-partner waves via LDS ----
    l_loc += __shfl_xor(l_loc, 16, 64);
    l_loc += __shfl_xor(l_loc, 32, 64);
    if (lane < 16) lred[w][li] = l_loc;
    __syncthreads();
    float linv[4];
    #pragma unroll
    for (int sb = 0; sb < 4; ++sb)
        linv[sb] = 1.0f / (lred[sb][li] + lred[sb + 4][li]);

    #pragma unroll
    for (int sb = 0; sb < 4; ++sb)
        #pragma unroll
        for (int ct = 0; ct < 2; ++ct) {
            const int c = c0 + ct * 16 + qd * 4;
            float* op = out + ((size_t)b * NC + c) * NN + i0 + 16 * sb + li;
            #pragma unroll
            for (int r = 0; r < 4; ++r)
                op[(size_t)r * NN] = o[sb][ct][r] * linv[sb];
        }
}

// ---------------------------------------------------------------------------
extern "C" void kernel_launch(void* const* d_in, const int* in_sizes, int n_in,
                              void* d_out, int out_size, void* d_ws, size_t ws_size,
                              hipStream_t stream) {
    const float* x  = (const float*)d_in[0];
    const float* Wq = (const float*)d_in[1];
    const float* bq = (const float*)d_in[2];
    const float* Wk = (const float*)d_in[3];
    const float* bk = (const float*)d_in[4];
    const float* Wv = (const float*)d_in[5];
    const float* bv = (const float*)d_in[6];
    float* out = (float*)d_out;

    unsigned short* q_ws = (unsigned short*)d_ws;            // 2 MB
    unsigned short* k_ws = q_ws + (size_t)NB * NN * ND;      // 2 MB
    unsigned short* v_ws = k_ws + (size_t)NB * NN * ND;      // 16 MB
    unsigned short* wp   = v_ws + (size_t)NB * NC * NN;      // 160 KB
    float*          bias = (float*)(wp + (size_t)NM * NC);   // 1.25 KB

    repack_kernel<<<NM * NC / 256, 256, 0, stream>>>(Wq, bq, Wk, bk, Wv, bv, wp, bias);
    proj_kernel<<<NB * (NN / 32), 256, 0, stream>>>(x, wp, bias, q_ws, k_ws, v_ws);
    attn_kernel<<<NB * (NN / 64), 512, 0, stream>>>(q_ws, k_ws, v_ws, out);
}